// Round 9
// baseline (988.602 us; speedup 1.0000x reference)
//
#include <hip/hip_runtime.h>
#include <math.h>

#define BB 512      // batch
#define TT 512      // seq len
#define DD 1024     // d_model
#define NF 256      // n_features
#define DE 256      // d_feat_emb
#define DH 512      // d_hidden
#define KK 64       // proto_num
#define PD 1024     // proto_dim
#define SPLIT 8            // feat t-chunks per batch
#define KSPLIT 16          // G1 K-chunks of 64
#define GB 256             // G1 blocks: 16 batch-tiles x 16 k-chunks
#define FEATB (BB * SPLIT) // 4096 feat blocks
#define CONSB (BB / 2)     // 256 consumer blocks

__device__ __forceinline__ float gelu_exact(float x) {
  return 0.5f * x * (1.0f + erff(x * 0.70710678118654752440f));
}

union Smem {
  struct { float As[64][36]; } g;                       // gemm role (9.2 KB)
  struct { float red[8][NF]; } f;                       // feat role (8 KB)
  struct {                                              // consumer (24.6 KB)
    float fm[2][NF];
    float fep[2][2][NF];
    float fe[2][NF];
    float hsp[2][2][DH];
    float hs[2][DH];
    float lred[2][8][KK];
    float gw[2][4];
    int   gi[2][4];
  } c;
};

// ---------------------------------------------------------------------------
// One fused kernel, three roles by blockIdx.x:
//  [0,256):          G1p[ks] partial GEMM (producer, signals gemm_cnt[by])
//  [256,4352):       feat partial sums   (producer, signals feat_cnt[b])
//  [4352,4608):      stage2 consumer: spin-wait on its 2 batches' producers,
//                    then fmean->femb->h->logits->top4->context.
// Cross-XCD visibility: __threadfence + release atomics / relaxed polls +
// __threadfence acquire (per Guideline 16).
// ---------------------------------------------------------------------------
__global__ __launch_bounds__(512) void fused_kernel(
    const float* __restrict__ hidden, const float* __restrict__ feat,
    const int* __restrict__ isl, const float* __restrict__ Wf,
    const float* __restrict__ bf, const float* __restrict__ W1,
    const float* __restrict__ b1, const float* __restrict__ W2,
    const float* __restrict__ b2, const float* __restrict__ proto,
    float* __restrict__ part, float* __restrict__ G1p,
    int* __restrict__ feat_cnt, int* __restrict__ gemm_cnt,
    float* __restrict__ weights, float* __restrict__ logits_out,
    float* __restrict__ context) {
  __shared__ Smem sm;
  int tid = threadIdx.x;   // 0..511
  int bid = blockIdx.x;

  if (bid < GB) {
    // ================= GEMM producer: 32 batches x 64 k's ==================
    int by = bid >> 4;   // batch tile 0..15
    int ks = bid & 15;   // k chunk 0..15
    int k0 = ks * 64;

    {
      int row = tid >> 4;       // 0..31
      int kq = tid & 15;        // 0..15 -> 4 k's each
      int b = by * 32 + row;
      int len = isl[b];
      len = len < 1 ? 1 : (len > TT ? TT : len);
      const float* ap = hidden + ((size_t)b * TT + (len - 1)) * DD + k0 + kq * 4;
      float4 a = *(const float4*)ap;
      sm.g.As[kq * 4 + 0][row] = a.x;
      sm.g.As[kq * 4 + 1][row] = a.y;
      sm.g.As[kq * 4 + 2][row] = a.z;
      sm.g.As[kq * 4 + 3][row] = a.w;
    }
    __syncthreads();

    int cg = tid & 63;   // cols cg*8..+7 (coalesced W1)
    int wg = tid >> 6;   // rows wg*4..+3 (wave-uniform -> LDS broadcast)
    const float* Bp = W1 + (size_t)k0 * DH + cg * 8;

    float acc[4][8];
#pragma unroll
    for (int i = 0; i < 4; ++i)
#pragma unroll
      for (int j = 0; j < 8; ++j) acc[i][j] = 0.f;

#pragma unroll 4
    for (int k = 0; k < 64; ++k) {
      float4 w0 = *(const float4*)(Bp + (size_t)k * DH);
      float4 w1 = *(const float4*)(Bp + (size_t)k * DH + 4);
      float4 a = *(const float4*)&sm.g.As[k][wg * 4];
      float aa[4] = {a.x, a.y, a.z, a.w};
      float ww[8] = {w0.x, w0.y, w0.z, w0.w, w1.x, w1.y, w1.z, w1.w};
#pragma unroll
      for (int i = 0; i < 4; ++i)
#pragma unroll
        for (int j = 0; j < 8; ++j) acc[i][j] += aa[i] * ww[j];
    }

#pragma unroll
    for (int i = 0; i < 4; ++i) {
      int brow = by * 32 + wg * 4 + i;
      float* dst = G1p + ((size_t)ks * BB + brow) * DH + cg * 8;
      float4 o0 = {acc[i][0], acc[i][1], acc[i][2], acc[i][3]};
      float4 o1 = {acc[i][4], acc[i][5], acc[i][6], acc[i][7]};
      *(float4*)dst = o0;
      *(float4*)(dst + 4) = o1;
    }
    __threadfence();
    __syncthreads();
    if (tid == 0)
      __hip_atomic_fetch_add(&gemm_cnt[by], 1, __ATOMIC_RELEASE,
                             __HIP_MEMORY_SCOPE_AGENT);
  } else if (bid < GB + FEATB) {
    // ================= feat producer: one (q, b) chunk =====================
    int fid = bid - GB;
    int q = fid >> 9;                         // 0..7
    int b = ((fid & 511) + 67 * q) & 511;     // tail-balance swizzle
    int len = isl[b];
    len = len < 1 ? 1 : (len > TT ? TT : len);
    int lo = (q * len) / SPLIT;
    int hi = ((q + 1) * len) / SPLIT;
    int wave = tid >> 6;
    int lane = tid & 63;
    const float* fb = feat + (size_t)b * TT * NF;

    float4 a0 = {0.f, 0.f, 0.f, 0.f}, a1 = a0;
    int t = lo + wave;
    for (; t + 8 < hi; t += 16) {
      float4 v0 = *(const float4*)(fb + (size_t)t * NF + lane * 4);
      float4 v1 = *(const float4*)(fb + (size_t)(t + 8) * NF + lane * 4);
      a0.x += v0.x; a0.y += v0.y; a0.z += v0.z; a0.w += v0.w;
      a1.x += v1.x; a1.y += v1.y; a1.z += v1.z; a1.w += v1.w;
    }
    for (; t < hi; t += 8) {
      float4 v0 = *(const float4*)(fb + (size_t)t * NF + lane * 4);
      a0.x += v0.x; a0.y += v0.y; a0.z += v0.z; a0.w += v0.w;
    }
    float4 acc;
    acc.x = a0.x + a1.x;
    acc.y = a0.y + a1.y;
    acc.z = a0.z + a1.z;
    acc.w = a0.w + a1.w;

    *(float4*)&sm.f.red[wave][lane * 4] = acc;
    __syncthreads();
    if (tid < NF) {
      int f = tid;
      float s = 0.f;
#pragma unroll
      for (int w = 0; w < 8; ++w) s += sm.f.red[w][f];
      part[((size_t)q * BB + b) * NF + f] = s;
    }
    __threadfence();
    __syncthreads();
    if (tid == 0)
      __hip_atomic_fetch_add(&feat_cnt[b], 1, __ATOMIC_RELEASE,
                             __HIP_MEMORY_SCOPE_AGENT);
  } else {
    // ================= stage2 consumer: 2 batches ==========================
    int pid = bid - GB - FEATB;
    int b0 = pid * 2;

    if (tid == 0) {
      while (__hip_atomic_load(&feat_cnt[b0], __ATOMIC_RELAXED,
                               __HIP_MEMORY_SCOPE_AGENT) < SPLIT ||
             __hip_atomic_load(&feat_cnt[b0 + 1], __ATOMIC_RELAXED,
                               __HIP_MEMORY_SCOPE_AGENT) < SPLIT ||
             __hip_atomic_load(&gemm_cnt[b0 >> 5], __ATOMIC_RELAXED,
                               __HIP_MEMORY_SCOPE_AGENT) < KSPLIT) {
        __builtin_amdgcn_s_sleep(8);
      }
      __threadfence();   // acquire: invalidate stale L1/L2 lines
    }
    __syncthreads();

    // ---- fmean ----
    {
      int bb = tid >> 8;
      int f = tid & 255;
      int b = b0 + bb;
      int len = isl[b];
      len = len < 1 ? 1 : (len > TT ? TT : len);
      float s = 0.f;
#pragma unroll
      for (int qq = 0; qq < SPLIT; ++qq)
        s += part[((size_t)qq * BB + b) * NF + f];
      sm.c.fm[bb][f] = s / (float)len;
    }
    __syncthreads();

    // ---- femb partials: K split 2x128 ----
    {
      int kh = tid >> 8;
      int col = tid & 255;
      float a0 = 0.f, a1 = 0.f;
      int i0 = kh * 128;
#pragma unroll 8
      for (int i = i0; i < i0 + 128; ++i) {
        float w = Wf[(size_t)i * DE + col];
        a0 += sm.c.fm[0][i] * w;
        a1 += sm.c.fm[1][i] * w;
      }
      sm.c.fep[kh][0][col] = a0;
      sm.c.fep[kh][1][col] = a1;
    }
    __syncthreads();

    // ---- femb combine ----
    {
      int bb = tid >> 8;
      int col = tid & 255;
      sm.c.fe[bb][col] = sm.c.fep[0][bb][col] + sm.c.fep[1][bb][col] + bf[col];
    }
    __syncthreads();

    // ---- h partials: K split 2x128 ----
    {
      int kh = tid >> 8;
      int c = tid & 255;
      const float* W1b = W1 + (size_t)DD * DH;
      float h00 = 0.f, h01 = 0.f, h10 = 0.f, h11 = 0.f;
      int i0 = kh * 128;
#pragma unroll 8
      for (int i = i0; i < i0 + 128; ++i) {
        float w0 = W1b[(size_t)i * DH + c];
        float w1 = W1b[(size_t)i * DH + c + 256];
        float f0 = sm.c.fe[0][i];
        float f1 = sm.c.fe[1][i];
        h00 += f0 * w0;
        h01 += f0 * w1;
        h10 += f1 * w0;
        h11 += f1 * w1;
      }
      sm.c.hsp[kh][0][c]       = h00;
      sm.c.hsp[kh][0][c + 256] = h01;
      sm.c.hsp[kh][1][c]       = h10;
      sm.c.hsp[kh][1][c + 256] = h11;
    }
    __syncthreads();

    // ---- h combine + G1p 16-way reduce + bias + gelu ----
    {
      int bb = tid >> 8;
      int c = tid & 255;
      int b = b0 + bb;
      float g0 = 0.f, g1 = 0.f;
#pragma unroll 4
      for (int ksI = 0; ksI < KSPLIT; ++ksI) {
        const float* gp = G1p + ((size_t)ksI * BB + b) * DH;
        g0 += gp[c];
        g1 += gp[c + 256];
      }
      float v0 = sm.c.hsp[0][bb][c] + sm.c.hsp[1][bb][c] + g0 + b1[c];
      float v1 = sm.c.hsp[0][bb][c + 256] + sm.c.hsp[1][bb][c + 256] + g1 +
                 b1[c + 256];
      sm.c.hs[bb][c]       = gelu_exact(v0);
      sm.c.hs[bb][c + 256] = gelu_exact(v1);
    }
    __syncthreads();

    // ---- logits partials: 8 segments of 64 over DH ----
    {
      int seg = tid >> 6;
      int j = tid & 63;
      float l0 = 0.f, l1 = 0.f;
      int i0 = seg * 64;
#pragma unroll 8
      for (int i = i0; i < i0 + 64; ++i) {
        float w = W2[(size_t)i * KK + j];
        l0 += sm.c.hs[0][i] * w;
        l1 += sm.c.hs[1][i] * w;
      }
      sm.c.lred[0][seg][j] = l0;
      sm.c.lred[1][seg][j] = l1;
    }
    __syncthreads();

    // ---- finalize logits + top-4 softmax gating ----
    if (tid < 128) {
      int bb = tid >> 6;
      int lane = tid & 63;
      float lg = b2[lane];
#pragma unroll
      for (int seg = 0; seg < 8; ++seg) lg += sm.c.lred[bb][seg][lane];
      logits_out[(size_t)(b0 + bb) * KK + lane] = lg;  // TEMP == 1.0

      float cur = lg;
      float tv[4];
      int ti[4];
#pragma unroll
      for (int r = 0; r < 4; ++r) {
        float mv = cur;
        int mi = lane;
#pragma unroll
        for (int off = 32; off; off >>= 1) {
          float ov = __shfl_xor(mv, off);
          int oi = __shfl_xor(mi, off);
          if (ov > mv || (ov == mv && oi < mi)) { mv = ov; mi = oi; }
        }
        tv[r] = mv;
        ti[r] = mi;
        if (lane == mi) cur = -INFINITY;
      }
      float m = tv[0];
      float e0 = expf(tv[0] - m), e1 = expf(tv[1] - m);
      float e2 = expf(tv[2] - m), e3 = expf(tv[3] - m);
      float inv = 1.0f / (e0 + e1 + e2 + e3);
      float w0 = e0 * inv, w1 = e1 * inv, w2 = e2 * inv, w3 = e3 * inv;

      float wt = 0.f;
      if (lane == ti[0]) wt = w0;
      else if (lane == ti[1]) wt = w1;
      else if (lane == ti[2]) wt = w2;
      else if (lane == ti[3]) wt = w3;
      weights[(size_t)(b0 + bb) * KK + lane] = wt;

      if (lane == 0) {
        sm.c.gw[bb][0] = w0; sm.c.gw[bb][1] = w1;
        sm.c.gw[bb][2] = w2; sm.c.gw[bb][3] = w3;
        sm.c.gi[bb][0] = ti[0]; sm.c.gi[bb][1] = ti[1];
        sm.c.gi[bb][2] = ti[2]; sm.c.gi[bb][3] = ti[3];
      }
    }
    __syncthreads();

    // ---- context = weights @ proto ----
    {
      int bb = tid >> 8;
      int off = (tid & 255) * 4;
      float w0 = sm.c.gw[bb][0], w1 = sm.c.gw[bb][1];
      float w2 = sm.c.gw[bb][2], w3 = sm.c.gw[bb][3];
      const float* p0 = proto + (size_t)sm.c.gi[bb][0] * PD;
      const float* p1 = proto + (size_t)sm.c.gi[bb][1] * PD;
      const float* p2 = proto + (size_t)sm.c.gi[bb][2] * PD;
      const float* p3 = proto + (size_t)sm.c.gi[bb][3] * PD;
      float4 r0 = *(const float4*)(p0 + off);
      float4 r1 = *(const float4*)(p1 + off);
      float4 r2 = *(const float4*)(p2 + off);
      float4 r3 = *(const float4*)(p3 + off);
      float4 o;
      o.x = w0 * r0.x + w1 * r1.x + w2 * r2.x + w3 * r3.x;
      o.y = w0 * r0.y + w1 * r1.y + w2 * r2.y + w3 * r3.y;
      o.z = w0 * r0.z + w1 * r1.z + w2 * r2.z + w3 * r3.z;
      o.w = w0 * r0.w + w1 * r1.w + w2 * r2.w + w3 * r3.w;
      *(float4*)(context + (size_t)(b0 + bb) * PD + off) = o;
    }
  }
}

// ---------------------------------------------------------------------------
extern "C" void kernel_launch(void* const* d_in, const int* in_sizes, int n_in,
                              void* d_out, int out_size, void* d_ws,
                              size_t ws_size, hipStream_t stream) {
  const float* hidden = (const float*)d_in[0];
  const float* feat   = (const float*)d_in[1];
  const int*   isl    = (const int*)d_in[2];
  const float* Wf     = (const float*)d_in[3];
  const float* bf     = (const float*)d_in[4];
  const float* W1     = (const float*)d_in[5];
  const float* b1     = (const float*)d_in[6];
  const float* W2     = (const float*)d_in[7];
  const float* b2     = (const float*)d_in[8];
  const float* proto  = (const float*)d_in[9];

  float* out = (float*)d_out;
  float* weights = out;                        // [B,K]
  float* logits  = out + (size_t)BB * KK;      // [B,K]
  float* context = out + (size_t)2 * BB * KK;  // [B,PD]

  float* ws = (float*)d_ws;
  float* part = ws;                                  // SPLIT*B*NF   (4 MB)
  float* G1p  = part + (size_t)SPLIT * BB * NF;      // KSPLIT*B*DH (16 MB)
  int* feat_cnt = (int*)(G1p + (size_t)KSPLIT * BB * DH);  // [BB]
  int* gemm_cnt = feat_cnt + BB;                           // [16]

  hipMemsetAsync(feat_cnt, 0, (BB + 16) * sizeof(int), stream);
  fused_kernel<<<GB + FEATB + CONSB, 512, 0, stream>>>(
      hidden, feat, isl, Wf, bf, W1, b1, W2, b2, proto, part, G1p, feat_cnt,
      gemm_cnt, weights, logits, context);
}

// Round 10
// 56.669 us; speedup vs baseline: 17.4451x; 17.4451x over previous
//
#include <hip/hip_runtime.h>
#include <math.h>

#define BB 512      // batch
#define TT 512      // seq len
#define DD 1024     // d_model
#define NF 256      // n_features
#define DE 256      // d_feat_emb
#define DH 512      // d_hidden
#define KK 64       // proto_num
#define PD 1024     // proto_dim
#define SPLIT 8            // feat t-chunks per batch (load balance)
#define KSPLIT 16          // G1 K-chunks of 64  (round-6/8 config)
#define GB 256             // G1 blocks: 16 batch-tiles x 16 k-chunks

__device__ __forceinline__ float gelu_exact(float x) {
  return 0.5f * x * (1.0f + erff(x * 0.70710678118654752440f));
}

// ---------------------------------------------------------------------------
// Kernel A (role-split):
//  blocks 0..255:     G1p[ks] = gather(hidden)[32 batches] @ W1[ks*64:+64, :]
//  blocks 256..4351:  part[q][b][f] = partial masked sums of feat (HBM-bound)
// Feat blocks use a q-dependent batch swizzle so each CU's resident set
// samples ~16 independent len draws (tail balance).
// ---------------------------------------------------------------------------
__global__ __launch_bounds__(256) void kernelA(
    const float* __restrict__ hidden, const float* __restrict__ feat,
    const int* __restrict__ isl, const float* __restrict__ W1,
    float* __restrict__ part, float* __restrict__ G1p) {
  __shared__ float As[64][36];   // As[k][batch_row]
  __shared__ float red[4][NF];

  int tid = threadIdx.x;

  if (blockIdx.x < GB) {
    int bid = blockIdx.x;
    int by = bid >> 4;   // batch tile 0..15
    int ks = bid & 15;   // k chunk 0..15
    int k0 = ks * 64;

    {
      int row = tid >> 3;
      int kq = tid & 7;
      int b = by * 32 + row;
      int len = isl[b];
      len = len < 1 ? 1 : (len > TT ? TT : len);
      const float* ap = hidden + ((size_t)b * TT + (len - 1)) * DD + k0 + kq * 8;
      float4 a0 = *(const float4*)ap;
      float4 a1 = *(const float4*)(ap + 4);
      As[kq * 8 + 0][row] = a0.x;
      As[kq * 8 + 1][row] = a0.y;
      As[kq * 8 + 2][row] = a0.z;
      As[kq * 8 + 3][row] = a0.w;
      As[kq * 8 + 4][row] = a1.x;
      As[kq * 8 + 5][row] = a1.y;
      As[kq * 8 + 6][row] = a1.z;
      As[kq * 8 + 7][row] = a1.w;
    }
    __syncthreads();

    int cg = tid & 63;
    int bg = tid >> 6;
    const float* Bp = W1 + (size_t)k0 * DH + cg * 8;

    float acc[8][8];
#pragma unroll
    for (int i = 0; i < 8; ++i)
#pragma unroll
      for (int j = 0; j < 8; ++j) acc[i][j] = 0.f;

#pragma unroll 4
    for (int k = 0; k < 64; ++k) {
      float4 w0 = *(const float4*)(Bp + (size_t)k * DH);
      float4 w1 = *(const float4*)(Bp + (size_t)k * DH + 4);
      float4 a0 = *(const float4*)&As[k][bg * 8];
      float4 a1 = *(const float4*)&As[k][bg * 8 + 4];
      float aa[8] = {a0.x, a0.y, a0.z, a0.w, a1.x, a1.y, a1.z, a1.w};
      float ww[8] = {w0.x, w0.y, w0.z, w0.w, w1.x, w1.y, w1.z, w1.w};
#pragma unroll
      for (int i = 0; i < 8; ++i)
#pragma unroll
        for (int j = 0; j < 8; ++j) acc[i][j] += aa[i] * ww[j];
    }

#pragma unroll
    for (int i = 0; i < 8; ++i) {
      int brow = by * 32 + bg * 8 + i;
      float* dst = G1p + ((size_t)ks * BB + brow) * DH + cg * 8;
      float4 o0 = {acc[i][0], acc[i][1], acc[i][2], acc[i][3]};
      float4 o1 = {acc[i][4], acc[i][5], acc[i][6], acc[i][7]};
      *(float4*)dst = o0;
      *(float4*)(dst + 4) = o1;
    }
  } else {
    int fid = blockIdx.x - GB;
    int q = fid >> 9;                         // 0..7
    int b = ((fid & 511) + 67 * q) & 511;     // swizzle: decorrelate CU's draws
    int len = isl[b];
    len = len < 1 ? 1 : (len > TT ? TT : len);
    int lo = (q * len) / SPLIT;
    int hi = ((q + 1) * len) / SPLIT;
    int wave = tid >> 6;
    int lane = tid & 63;
    const float* fb = feat + (size_t)b * TT * NF;

    float4 a0 = {0.f, 0.f, 0.f, 0.f}, a1 = a0, a2 = a0, a3 = a0;
    int t = lo + wave;
    for (; t + 12 < hi; t += 16) {
      float4 v0 = *(const float4*)(fb + (size_t)t * NF + lane * 4);
      float4 v1 = *(const float4*)(fb + (size_t)(t + 4) * NF + lane * 4);
      float4 v2 = *(const float4*)(fb + (size_t)(t + 8) * NF + lane * 4);
      float4 v3 = *(const float4*)(fb + (size_t)(t + 12) * NF + lane * 4);
      a0.x += v0.x; a0.y += v0.y; a0.z += v0.z; a0.w += v0.w;
      a1.x += v1.x; a1.y += v1.y; a1.z += v1.z; a1.w += v1.w;
      a2.x += v2.x; a2.y += v2.y; a2.z += v2.z; a2.w += v2.w;
      a3.x += v3.x; a3.y += v3.y; a3.z += v3.z; a3.w += v3.w;
    }
    for (; t < hi; t += 4) {
      float4 v0 = *(const float4*)(fb + (size_t)t * NF + lane * 4);
      a0.x += v0.x; a0.y += v0.y; a0.z += v0.z; a0.w += v0.w;
    }
    float4 acc;
    acc.x = a0.x + a1.x + a2.x + a3.x;
    acc.y = a0.y + a1.y + a2.y + a3.y;
    acc.z = a0.z + a1.z + a2.z + a3.z;
    acc.w = a0.w + a1.w + a2.w + a3.w;

    *(float4*)&red[wave][lane * 4] = acc;
    __syncthreads();
    int f = tid;
    float s = red[0][f] + red[1][f] + red[2][f] + red[3][f];
    part[((size_t)q * BB + b) * NF + f] = s;
  }
}

// ---------------------------------------------------------------------------
// Kernel B: fused stage 2 (round-8 structure; SPLIT=8 part reduce, KSPLIT=16).
// 256 blocks x 512 threads (2 waves/SIMD), 2 batches per block.
// ---------------------------------------------------------------------------
__global__ __launch_bounds__(512) void stage2_kernel(
    const int* __restrict__ isl, const float* __restrict__ part,
    const float* __restrict__ Wf, const float* __restrict__ bf,
    const float* __restrict__ W1, const float* __restrict__ b1,
    const float* __restrict__ G1p, const float* __restrict__ W2,
    const float* __restrict__ b2, const float* __restrict__ proto,
    float* __restrict__ weights, float* __restrict__ logits_out,
    float* __restrict__ context) {
  int tid = threadIdx.x;           // 0..511
  int b0 = blockIdx.x * 2;

  __shared__ float fm[2][NF];         // fmean
  __shared__ float fep[2][2][NF];     // femb partials [khalf][bb][col]
  __shared__ float fe[2][NF];         // femb
  __shared__ float hsp[2][2][DH];     // h partials [khalf][bb][col]
  __shared__ float hs[2][DH];         // gelu output
  __shared__ float lred[2][8][KK];    // logits partials [bb][seg][j]
  __shared__ float gw[2][4];
  __shared__ int   gi[2][4];

  // ---- fmean: 512 outputs (bb, f), 8 partials each ----
  {
    int bb = tid >> 8;
    int f = tid & 255;
    int b = b0 + bb;
    int len = isl[b];
    len = len < 1 ? 1 : (len > TT ? TT : len);
    float s = 0.f;
#pragma unroll
    for (int qq = 0; qq < SPLIT; ++qq)
      s += part[((size_t)qq * BB + b) * NF + f];
    fm[bb][f] = s / (float)len;
  }
  __syncthreads();

  // ---- femb partials: K split 2x128, both batches per thread ----
  {
    int kh = tid >> 8;
    int col = tid & 255;
    float a0 = 0.f, a1 = 0.f;
    int i0 = kh * 128;
#pragma unroll 8
    for (int i = i0; i < i0 + 128; ++i) {
      float w = Wf[(size_t)i * DE + col];
      a0 += fm[0][i] * w;
      a1 += fm[1][i] * w;
    }
    fep[kh][0][col] = a0;
    fep[kh][1][col] = a1;
  }
  __syncthreads();

  // ---- femb combine ----
  {
    int bb = tid >> 8;
    int col = tid & 255;
    fe[bb][col] = fep[0][bb][col] + fep[1][bb][col] + bf[col];
  }
  __syncthreads();

  // ---- h partials: K split 2x128; thread (kh,c) does cols c, c+256, both b
  {
    int kh = tid >> 8;
    int c = tid & 255;
    const float* W1b = W1 + (size_t)DD * DH;
    float h00 = 0.f, h01 = 0.f, h10 = 0.f, h11 = 0.f;
    int i0 = kh * 128;
#pragma unroll 8
    for (int i = i0; i < i0 + 128; ++i) {
      float w0 = W1b[(size_t)i * DH + c];
      float w1 = W1b[(size_t)i * DH + c + 256];
      float f0 = fe[0][i];
      float f1 = fe[1][i];
      h00 += f0 * w0;
      h01 += f0 * w1;
      h10 += f1 * w0;
      h11 += f1 * w1;
    }
    hsp[kh][0][c]       = h00;
    hsp[kh][0][c + 256] = h01;
    hsp[kh][1][c]       = h10;
    hsp[kh][1][c + 256] = h11;
  }
  __syncthreads();

  // ---- h combine + G1p 16-way reduce + bias + gelu ----
  {
    int bb = tid >> 8;
    int c = tid & 255;
    int b = b0 + bb;
    float g0 = 0.f, g1 = 0.f;
#pragma unroll 4
    for (int ksI = 0; ksI < KSPLIT; ++ksI) {
      const float* gp = G1p + ((size_t)ksI * BB + b) * DH;
      g0 += gp[c];
      g1 += gp[c + 256];
    }
    float v0 = hsp[0][bb][c] + hsp[1][bb][c] + g0 + b1[c];
    float v1 = hsp[0][bb][c + 256] + hsp[1][bb][c + 256] + g1 + b1[c + 256];
    hs[bb][c]       = gelu_exact(v0);
    hs[bb][c + 256] = gelu_exact(v1);
  }
  __syncthreads();

  // ---- logits partials: 8 segments of 64 over DH, both batches ----
  {
    int seg = tid >> 6;   // 0..7
    int j = tid & 63;
    float l0 = 0.f, l1 = 0.f;
    int i0 = seg * 64;
#pragma unroll 8
    for (int i = i0; i < i0 + 64; ++i) {
      float w = W2[(size_t)i * KK + j];
      l0 += hs[0][i] * w;
      l1 += hs[1][i] * w;
    }
    lred[0][seg][j] = l0;
    lred[1][seg][j] = l1;
  }
  __syncthreads();

  // ---- finalize logits + top-4 softmax gating (wave0 -> b0, wave1 -> b1) --
  if (tid < 128) {
    int bb = tid >> 6;
    int lane = tid & 63;
    float lg = b2[lane];
#pragma unroll
    for (int seg = 0; seg < 8; ++seg) lg += lred[bb][seg][lane];
    logits_out[(size_t)(b0 + bb) * KK + lane] = lg;  // TEMP == 1.0

    float cur = lg;
    float tv[4];
    int ti[4];
#pragma unroll
    for (int r = 0; r < 4; ++r) {
      float mv = cur;
      int mi = lane;
#pragma unroll
      for (int off = 32; off; off >>= 1) {
        float ov = __shfl_xor(mv, off);
        int oi = __shfl_xor(mi, off);
        if (ov > mv || (ov == mv && oi < mi)) { mv = ov; mi = oi; }
      }
      tv[r] = mv;
      ti[r] = mi;
      if (lane == mi) cur = -INFINITY;
    }
    float m = tv[0];
    float e0 = expf(tv[0] - m), e1 = expf(tv[1] - m);
    float e2 = expf(tv[2] - m), e3 = expf(tv[3] - m);
    float inv = 1.0f / (e0 + e1 + e2 + e3);
    float w0 = e0 * inv, w1 = e1 * inv, w2 = e2 * inv, w3 = e3 * inv;

    float wt = 0.f;
    if (lane == ti[0]) wt = w0;
    else if (lane == ti[1]) wt = w1;
    else if (lane == ti[2]) wt = w2;
    else if (lane == ti[3]) wt = w3;
    weights[(size_t)(b0 + bb) * KK + lane] = wt;

    if (lane == 0) {
      gw[bb][0] = w0; gw[bb][1] = w1; gw[bb][2] = w2; gw[bb][3] = w3;
      gi[bb][0] = ti[0]; gi[bb][1] = ti[1]; gi[bb][2] = ti[2]; gi[bb][3] = ti[3];
    }
  }
  __syncthreads();

  // ---- context = weights @ proto: thread (bb, idx) -> one float4 ----
  {
    int bb = tid >> 8;
    int off = (tid & 255) * 4;
    float w0 = gw[bb][0], w1 = gw[bb][1], w2 = gw[bb][2], w3 = gw[bb][3];
    const float* p0 = proto + (size_t)gi[bb][0] * PD;
    const float* p1 = proto + (size_t)gi[bb][1] * PD;
    const float* p2 = proto + (size_t)gi[bb][2] * PD;
    const float* p3 = proto + (size_t)gi[bb][3] * PD;
    float4 r0 = *(const float4*)(p0 + off);
    float4 r1 = *(const float4*)(p1 + off);
    float4 r2 = *(const float4*)(p2 + off);
    float4 r3 = *(const float4*)(p3 + off);
    float4 o;
    o.x = w0 * r0.x + w1 * r1.x + w2 * r2.x + w3 * r3.x;
    o.y = w0 * r0.y + w1 * r1.y + w2 * r2.y + w3 * r3.y;
    o.z = w0 * r0.z + w1 * r1.z + w2 * r2.z + w3 * r3.z;
    o.w = w0 * r0.w + w1 * r1.w + w2 * r2.w + w3 * r3.w;
    *(float4*)(context + (size_t)(b0 + bb) * PD + off) = o;
  }
}

// ---------------------------------------------------------------------------
extern "C" void kernel_launch(void* const* d_in, const int* in_sizes, int n_in,
                              void* d_out, int out_size, void* d_ws,
                              size_t ws_size, hipStream_t stream) {
  const float* hidden = (const float*)d_in[0];
  const float* feat   = (const float*)d_in[1];
  const int*   isl    = (const int*)d_in[2];
  const float* Wf     = (const float*)d_in[3];
  const float* bf     = (const float*)d_in[4];
  const float* W1     = (const float*)d_in[5];
  const float* b1     = (const float*)d_in[6];
  const float* W2     = (const float*)d_in[7];
  const float* b2     = (const float*)d_in[8];
  const float* proto  = (const float*)d_in[9];

  float* out = (float*)d_out;
  float* weights = out;                        // [B,K]
  float* logits  = out + (size_t)BB * KK;      // [B,K]
  float* context = out + (size_t)2 * BB * KK;  // [B,PD]

  float* ws = (float*)d_ws;
  float* part = ws;                                  // SPLIT*B*NF (4 MB)
  float* G1p  = part + (size_t)SPLIT * BB * NF;      // KSPLIT*B*DH (16 MB)

  kernelA<<<GB + BB * SPLIT, 256, 0, stream>>>(hidden, feat, isl, W1, part, G1p);
  stage2_kernel<<<BB / 2, 512, 0, stream>>>(isl, part, Wf, bf, W1, b1, G1p, W2,
                                            b2, proto, weights, logits, context);
}